// Round 13
// baseline (81.252 us; speedup 1.0000x reference)
//
#include <hip/hip_runtime.h>

#define NBODY 8192
#define BLOCK 256
#define SLABS 32
#define JCHUNK (NBODY / SLABS)   // 256 j-bodies per block (== BLOCK)
#define PHASE 8                  // pair-chains forced in flight per batch
#define NPHASE (JCHUNK / PHASE)  // 32
#define SOFT2 1.0e-4f            // 0.01^2

// R9 shell (best: 78.2; grid 32x32, 4 waves/SIMD proven optimal over {2,8})
// with ONE change: the inner loop is phase-split into three array passes --
// (A) 8x independent dx/dy/dz/r2, (B) 8x v_rsq issued back-to-back,
// (C) 8x w + accumulate. Rationale: VALUBusy ~36% with issue model ~11-13us
// vs force ~36us = 2/3 idle issue port; all memory pipes exonerated
// (DS demand varied 4x with no time change, SGPR path worse, HBM ~0).
// Remaining suspect: compiler keeps only ~2-3 serial pair-chains in flight
// (VGPR_Count=48 of 128 budget!), so the mid-chain rsq dependent-latency
// can't be covered by 4 waves. Explicit arrays + full unroll (static
// indices -> registers) force 8 chains in flight and put >=8 issue slots
// between every rsq and its consumer.
__global__ __launch_bounds__(BLOCK, 4) void nbody_kernel(
    const float* __restrict__ pos, const float* __restrict__ mass,
    float* __restrict__ out) {
  __shared__ float4 tile[JCHUNK];

  const int t = threadIdx.x;
  const int i = blockIdx.x * BLOCK + t;
  const int j = blockIdx.y * JCHUNK + t;  // JCHUNK == BLOCK

  tile[t] = make_float4(pos[j * 3 + 0], pos[j * 3 + 1], pos[j * 3 + 2],
                        mass[j]);

  const float xi = pos[i * 3 + 0];
  const float yi = pos[i * 3 + 1];
  const float zi = pos[i * 3 + 2];

  __syncthreads();

  float ax = 0.f, ay = 0.f, az = 0.f;

  for (int c = 0; c < NPHASE; ++c) {
    // Load batch (8 wave-uniform ds_read_b128, single lgkm wait).
    float4 jt[PHASE];
#pragma unroll
    for (int u = 0; u < PHASE; ++u) jt[u] = tile[c * PHASE + u];

    // Phase A: 8 independent difference/r2 chains.
    float dx[PHASE], dy[PHASE], dz[PHASE], r2[PHASE];
#pragma unroll
    for (int u = 0; u < PHASE; ++u) {
      dx[u] = jt[u].x - xi;
      dy[u] = jt[u].y - yi;
      dz[u] = jt[u].z - zi;
      r2[u] = fmaf(dx[u], dx[u],
                   fmaf(dy[u], dy[u], fmaf(dz[u], dz[u], SOFT2)));
    }

    // Phase B: 8 rsq issued back-to-back; first consumer is >=8 slots away.
    float inv[PHASE];
#pragma unroll
    for (int u = 0; u < PHASE; ++u) inv[u] = __builtin_amdgcn_rsqf(r2[u]);

    // Phase C: 8 independent weight/accumulate chains (ax/ay/az are three
    // interleaved chains; >=10 issue slots between same-chain fmas).
#pragma unroll
    for (int u = 0; u < PHASE; ++u) {
      float w = jt[u].w * ((inv[u] * inv[u]) * inv[u]);  // m_j * r^-3
      ax = fmaf(w, dx[u], ax);
      ay = fmaf(w, dy[u], ay);
      az = fmaf(w, dz[u], az);
    }
  }

  // 32 slabs contend per address (R0/R9-proven; L2-side float adds).
  atomicAdd(&out[i * 3 + 0], ax);
  atomicAdd(&out[i * 3 + 1], ay);
  atomicAdd(&out[i * 3 + 2], az);
}

extern "C" void kernel_launch(void* const* d_in, const int* in_sizes, int n_in,
                              void* d_out, int out_size, void* d_ws,
                              size_t ws_size, hipStream_t stream) {
  const float* pos = (const float*)d_in[0];
  const float* mass = (const float*)d_in[1];
  float* out = (float*)d_out;

  // d_out is re-poisoned to 0xAA before every launch; atomics need zeros.
  hipMemsetAsync(d_out, 0, (size_t)out_size * sizeof(float), stream);

  nbody_kernel<<<dim3(NBODY / BLOCK, SLABS), BLOCK, 0, stream>>>(pos, mass,
                                                                 out);
}

// Round 14
// 78.315 us; speedup vs baseline: 1.0375x; 1.0375x over previous
//
#include <hip/hip_runtime.h>

#define NBODY 8192
#define BLOCK 256
#define SLABS 32
#define JCHUNK (NBODY / SLABS)   // 256 j-bodies per block (== BLOCK)
#define PHASE 16                 // j-bodies register-hoisted per burst
#define NPHASE (JCHUNK / PHASE)  // 16
#define SOFT2 1.0e-4f            // 0.01^2

// R9 shell (best: 78.2; IPT=1, grid 32x32, 4 waves/SIMD — measured optimum
// over every scheduling axis) + the session's one remaining measured-positive
// lever: instruction count (R7: marginal ops bill ~0.85us per op/pair).
// R8's quadratic expansion (passed, absmax 16) ported here at 11 slots/pair:
//   A_j = (-2x, -2y, -2z, nj+SOFT2) staged as float4,
//   mm  = -m/2 packed 4-per-float4,
//   r2  = A.x*xi + A.y*yi + A.z*zi + (A.w*1.0 + ni)   -> 4 fma (inline 1.0)
//   W   = mm * inv^3                                  -> rsq + 3 mul
//   S  += W*A.xyz ; sw += W                           -> 3 fma + 1 fmac
//   epilogue: a_i = S + 2*sw*p_i (un-scales the -2/-m2 basis), 1 fma/comp.
// 11 slots vs R9's 12; DS/pair = (16 b128 + 4 b128)/16 j = ~15cy (pipe ok).
__global__ __launch_bounds__(BLOCK, 4) void nbody_kernel(
    const float* __restrict__ pos, const float* __restrict__ mass,
    float* __restrict__ out) {
  __shared__ float4 tile[JCHUNK];      // (-2x, -2y, -2z, nj + SOFT2)
  __shared__ float4 mmt[JCHUNK / 4];   // -m/2, packed x4

  const int t = threadIdx.x;
  const int i = blockIdx.x * BLOCK + t;
  const int j = blockIdx.y * JCHUNK + t;  // JCHUNK == BLOCK

  {
    const float jx = pos[j * 3 + 0];
    const float jy = pos[j * 3 + 1];
    const float jz = pos[j * 3 + 2];
    tile[t] = make_float4(-2.f * jx, -2.f * jy, -2.f * jz,
                          fmaf(jx, jx, fmaf(jy, jy, fmaf(jz, jz, SOFT2))));
    if (t < JCHUNK / 4) {
      const int jb = blockIdx.y * JCHUNK + 4 * t;
      mmt[t] = make_float4(-0.5f * mass[jb + 0], -0.5f * mass[jb + 1],
                           -0.5f * mass[jb + 2], -0.5f * mass[jb + 3]);
    }
  }

  const float xi = pos[i * 3 + 0];
  const float yi = pos[i * 3 + 1];
  const float zi = pos[i * 3 + 2];
  const float ni = fmaf(xi, xi, fmaf(yi, yi, zi * zi));

  __syncthreads();

  float Sx = 0.f, Sy = 0.f, Sz = 0.f, sw = 0.f;

  for (int c = 0; c < NPHASE; ++c) {
    // Burst-hoist: 16 + 4 wave-uniform ds_read_b128, single lgkm wait.
    float4 jt[PHASE];
    float4 mm[PHASE / 4];
#pragma unroll
    for (int u = 0; u < PHASE; ++u) jt[u] = tile[c * PHASE + u];
#pragma unroll
    for (int u = 0; u < PHASE / 4; ++u) mm[u] = mmt[c * (PHASE / 4) + u];
    const float* mmf = (const float*)mm;

    // 11 full-rate slots + 1 trans per pair.
#pragma unroll
    for (int u = 0; u < PHASE; ++u) {
      float r2 = fmaf(jt[u].x, xi,
                 fmaf(jt[u].y, yi,
                 fmaf(jt[u].z, zi, fmaf(jt[u].w, 1.0f, ni))));
      float inv = __builtin_amdgcn_rsqf(r2);   // v_rsq_f32
      float W = mmf[u] * ((inv * inv) * inv);  // -m_j/2 * r^-3
      Sx = fmaf(W, jt[u].x, Sx);               // accumulates +m_j r^-3 x_j
      Sy = fmaf(W, jt[u].y, Sy);
      Sz = fmaf(W, jt[u].z, Sz);
      sw = fmaf(W, 1.0f, sw);                  // -(1/2) sum m_j r^-3
    }
  }

  // a_i = S + 2*sw*p_i ; 32-way atomics (R0/R9-proven, ~free at 32).
  const float s2 = sw + sw;
  atomicAdd(&out[i * 3 + 0], fmaf(s2, xi, Sx));
  atomicAdd(&out[i * 3 + 1], fmaf(s2, yi, Sy));
  atomicAdd(&out[i * 3 + 2], fmaf(s2, zi, Sz));
}

extern "C" void kernel_launch(void* const* d_in, const int* in_sizes, int n_in,
                              void* d_out, int out_size, void* d_ws,
                              size_t ws_size, hipStream_t stream) {
  const float* pos = (const float*)d_in[0];
  const float* mass = (const float*)d_in[1];
  float* out = (float*)d_out;

  // d_out is re-poisoned to 0xAA before every launch; atomics need zeros.
  hipMemsetAsync(d_out, 0, (size_t)out_size * sizeof(float), stream);

  nbody_kernel<<<dim3(NBODY / BLOCK, SLABS), BLOCK, 0, stream>>>(pos, mass,
                                                                 out);
}